// Round 1
// baseline (5296.769 us; speedup 1.0000x reference)
//
#include <hip/hip_runtime.h>
#include <hip/hip_fp16.h>
#include <cstdint>
#include <cstddef>

#define BB 64      // batch
#define TT 2048    // time
#define DD 256     // input dim
#define HH 256     // hidden
#define G4 1024    // 4*H

typedef unsigned int u32;

// ---------------- activation helpers (fp32) ----------------
__device__ __forceinline__ float sigf(float x) {
    return 1.0f / (1.0f + __expf(-x));
}
__device__ __forceinline__ float tanhfast(float x) {
    float ax = fabsf(x);
    float t  = __expf(-2.0f * ax);
    float r  = (1.0f - t) / (1.0f + t);
    return copysignf(r, x);
}

// ---------------- f16 dot2 ----------------
#if defined(__has_builtin)
#if __has_builtin(__builtin_amdgcn_fdot2)
#define HAVE_FDOT2 1
#endif
#endif

typedef _Float16 f16x2 __attribute__((ext_vector_type(2)));

__device__ __forceinline__ float dot2f(u32 a, u32 b, float c) {
#ifdef HAVE_FDOT2
    return __builtin_amdgcn_fdot2(__builtin_bit_cast(f16x2, a),
                                  __builtin_bit_cast(f16x2, b), c, false);
#else
    __half2 ah = *reinterpret_cast<__half2*>(&a);
    __half2 bh = *reinterpret_cast<__half2*>(&b);
    float2 af = __half22float2(ah), bf = __half22float2(bh);
    return c + af.x * bf.x + af.y * bf.y;
#endif
}

// ---------------- prep: pack W_h (rows D..D+H) into f16 pairs along k ----------------
// whp[k2][c] = half2( W[D+2k2][c], W[D+2k2+1][c] ),  k2 in [0,128), c in [0,1024)
__global__ __launch_bounds__(256) void prep_wh(const float* __restrict__ W, u32* __restrict__ whp) {
    int idx = blockIdx.x * 256 + threadIdx.x;   // < 131072
    int k2 = idx >> 10, c = idx & 1023;
    float lo = W[(size_t)(DD + 2 * k2) * G4 + c];
    float hi = W[(size_t)(DD + 2 * k2 + 1) * G4 + c];
    __half2 h = __floats2half2_rn(lo, hi);
    whp[idx] = *reinterpret_cast<u32*>(&h);
}

// ---------------- init state c,h = 0 ----------------
__global__ __launch_bounds__(256) void init_state(float* __restrict__ cst, float* __restrict__ hst) {
    int i = blockIdx.x * 256 + threadIdx.x;     // < 16384
    cst[i] = 0.0f;
    hst[i] = 0.0f;
}

// ---------------- GEMM: xw[m][n] = bias[n] + sum_k x_row(m)[k] * W[k][n]  (k<D) ----------------
// m-space per chunk: m = b*ct + (t - t0). Tile 128x64, BK=32, 256 threads.
#define BM 128
#define BN 64
#define BK 32

__global__ __launch_bounds__(256) void gemm_xw(const float* __restrict__ x,
                                               const float* __restrict__ W,
                                               const float* __restrict__ bias,
                                               const int* __restrict__ seqlen,
                                               float* __restrict__ xw,
                                               int t0, int ct) {
    const int m0 = blockIdx.x * BM;
    const int b  = m0 / ct;
    const int tl0 = m0 - b * ct;
    if (t0 + tl0 >= seqlen[b]) return;          // whole tile past this batch's length
    const int n0 = blockIdx.y * BN;

    __shared__ __align__(16) float xs[BK][BM + 4];  // stride 132 floats: 16B-aligned rows
    __shared__ __align__(16) float wsm[BK][BN];

    const int tid = threadIdx.x;
    const int tx = tid & 15, ty = tid >> 4;
    const float* xrowbase = x + ((size_t)b * TT + t0 + tl0) * DD;

    float4 acc[8];
    #pragma unroll
    for (int i = 0; i < 8; ++i) acc[i] = make_float4(0.f, 0.f, 0.f, 0.f);

    for (int k0 = 0; k0 < DD; k0 += BK) {
        #pragma unroll
        for (int i = 0; i < 4; ++i) {
            int idx = tid + i * 256;            // 0..1023
            int r = idx >> 3, kv = idx & 7;
            float4 v = *reinterpret_cast<const float4*>(xrowbase + (size_t)r * DD + k0 + kv * 4);
            xs[kv * 4 + 0][r] = v.x; xs[kv * 4 + 1][r] = v.y;
            xs[kv * 4 + 2][r] = v.z; xs[kv * 4 + 3][r] = v.w;
        }
        #pragma unroll
        for (int i = 0; i < 2; ++i) {
            int idx = tid + i * 256;            // 0..511
            int kr = idx >> 4, cv = idx & 15;
            *reinterpret_cast<float4*>(&wsm[kr][cv * 4]) =
                *reinterpret_cast<const float4*>(W + (size_t)(k0 + kr) * G4 + n0 + cv * 4);
        }
        __syncthreads();
        #pragma unroll
        for (int k = 0; k < BK; ++k) {
            float4 a0 = *reinterpret_cast<const float4*>(&xs[k][ty * 8]);
            float4 a1 = *reinterpret_cast<const float4*>(&xs[k][ty * 8 + 4]);
            float4 bv = *reinterpret_cast<const float4*>(&wsm[k][tx * 4]);
            float ai[8] = {a0.x, a0.y, a0.z, a0.w, a1.x, a1.y, a1.z, a1.w};
            #pragma unroll
            for (int i = 0; i < 8; ++i) {
                acc[i].x += ai[i] * bv.x; acc[i].y += ai[i] * bv.y;
                acc[i].z += ai[i] * bv.z; acc[i].w += ai[i] * bv.w;
            }
        }
        __syncthreads();
    }
    float4 bv = *reinterpret_cast<const float4*>(bias + n0 + tx * 4);
    float* outbase = xw + (size_t)m0 * G4 + n0 + tx * 4;
    #pragma unroll
    for (int i = 0; i < 8; ++i) {
        float4 o = make_float4(acc[i].x + bv.x, acc[i].y + bv.y,
                               acc[i].z + bv.z, acc[i].w + bv.w);
        *reinterpret_cast<float4*>(outbase + (size_t)(ty * 8 + i) * G4) = o;
    }
}

// ---------------- recurrent LSTM chunk ----------------
// 64 blocks (one per batch element) x 512 threads.
// Thread t owns gate columns {2t, 2t+1}. W_h(f16 pairs): k2 in [0,96) in VGPRs,
// k2 in [96,128) in LDS. h kept as f16 in LDS (broadcast reads).
#define NT 512
#define KREG 96   // k2 pairs held in registers
#define KLDS 32   // k2 pairs held in LDS

__global__ __launch_bounds__(NT, 2) void lstm_chunk(const u32* __restrict__ whp,
                                                    const float* __restrict__ xw,
                                                    const int* __restrict__ seqlen,
                                                    float* __restrict__ y,
                                                    float* __restrict__ cst,
                                                    float* __restrict__ hst,
                                                    int t0, int ct) {
    __shared__ __align__(16) u32 w2lds[KLDS * 1024];   // 128 KB
    __shared__ __align__(16) float g_sh[G4];           // 4 KB
    __shared__ __align__(16) u32 h_sh_u[128];          // 256 x f16 = 512 B

    const int tid = threadIdx.x;
    const int b   = blockIdx.x;
    const int slen = seqlen[b];

    // --- load register-resident part of W_h: 96 x uint2 (192 VGPRs) ---
    uint2 wr[KREG];
    #pragma unroll
    for (int i = 0; i < KREG; ++i)
        wr[i] = *reinterpret_cast<const uint2*>(whp + (size_t)i * 1024 + 2 * tid);

    // --- stage LDS part of W_h: rows k2 = 96..127 (32768 u32) ---
    {
        const uint4* src = reinterpret_cast<const uint4*>(whp + KREG * 1024);
        uint4* dst = reinterpret_cast<uint4*>(w2lds);
        for (int i = tid; i < (KLDS * 1024) / 4; i += NT) dst[i] = src[i];
    }

    // --- load state ---
    __half* hs = reinterpret_cast<__half*>(h_sh_u);
    float c_r = 0.0f;
    if (tid < HH) {
        c_r = cst[b * HH + tid];
        hs[tid] = __float2half(hst[b * HH + tid]);
    }
    __syncthreads();

    const float* xwbase = xw + (size_t)b * ct * G4 + 2 * tid;
    float2 xwcur = *reinterpret_cast<const float2*>(xwbase);
    const uint4* h4 = reinterpret_cast<const uint4*>(h_sh_u);

    int tl = 0;
    for (; tl < ct; ++tl) {
        if (t0 + tl >= slen) break;

        // prefetch next xw row (consumed next iteration; latency hidden by dot loop)
        float2 xwnext = xwcur;
        if (tl + 1 < ct)
            xwnext = *reinterpret_cast<const float2*>(xwbase + (size_t)(tl + 1) * G4);

        float a0 = xwcur.x, a1 = xwcur.y;

        // register part: k2 in [0,96)
        #pragma unroll
        for (int kb = 0; kb < KREG / 4; ++kb) {
            uint4 hh = h4[kb];                 // broadcast: 8 h values (4 k2 pairs)
            a0 = dot2f(hh.x, wr[4 * kb + 0].x, a0); a1 = dot2f(hh.x, wr[4 * kb + 0].y, a1);
            a0 = dot2f(hh.y, wr[4 * kb + 1].x, a0); a1 = dot2f(hh.y, wr[4 * kb + 1].y, a1);
            a0 = dot2f(hh.z, wr[4 * kb + 2].x, a0); a1 = dot2f(hh.z, wr[4 * kb + 2].y, a1);
            a0 = dot2f(hh.w, wr[4 * kb + 3].x, a0); a1 = dot2f(hh.w, wr[4 * kb + 3].y, a1);
        }
        // LDS part: k2 in [96,128)
        #pragma unroll
        for (int kb = KREG / 4; kb < 32; ++kb) {
            uint4 hh = h4[kb];
            #pragma unroll
            for (int j = 0; j < 4; ++j) {
                int row = 4 * kb + j - KREG;
                uint2 wl = *reinterpret_cast<const uint2*>(&w2lds[row * 1024 + 2 * tid]);
                u32 hj = (j == 0) ? hh.x : (j == 1) ? hh.y : (j == 2) ? hh.z : hh.w;
                a0 = dot2f(hj, wl.x, a0);
                a1 = dot2f(hj, wl.y, a1);
            }
        }

        *reinterpret_cast<float2*>(&g_sh[2 * tid]) = make_float2(a0, a1);
        __syncthreads();

        if (tid < HH) {
            float gi = g_sh[tid];
            float gj = g_sh[HH + tid];
            float gf = g_sh[2 * HH + tid];
            float go = g_sh[3 * HH + tid];
            float nc = c_r * sigf(gf + 1.0f) + sigf(gi) * tanhfast(gj);
            float nh = tanhfast(nc) * sigf(go);
            c_r = nc;
            hs[tid] = __float2half(nh);
            y[((size_t)b * TT + t0 + tl) * HH + tid] = nh;
        }
        __syncthreads();
        xwcur = xwnext;
    }

    // zero-fill masked tail of this chunk (reference outputs 0 past seq_len)
    if (tl < ct) {
        float4 z = make_float4(0.f, 0.f, 0.f, 0.f);
        size_t base = ((size_t)b * TT + t0 + tl) * HH;
        size_t total = (size_t)(ct - tl) * HH;
        for (size_t i = 4 * (size_t)tid; i < total; i += 4 * NT)
            *reinterpret_cast<float4*>(y + base + i) = z;
    }

    // persist state for next chunk
    if (tid < HH) {
        cst[b * HH + tid] = c_r;
        hst[b * HH + tid] = __half2float(hs[tid]);
    }
}

// ---------------- host ----------------
extern "C" void kernel_launch(void* const* d_in, const int* in_sizes, int n_in,
                              void* d_out, int out_size, void* d_ws, size_t ws_size,
                              hipStream_t stream) {
    (void)in_sizes; (void)n_in; (void)out_size;
    const float* x      = (const float*)d_in[0];
    const float* W      = (const float*)d_in[1];
    const float* bias   = (const float*)d_in[2];
    const int*   seqlen = (const int*)d_in[3];
    float* y = (float*)d_out;

    // workspace layout: [whp 512KB][c 64KB][h 64KB][xw chunk buffer ...]
    u32*   whp = (u32*)d_ws;
    float* cst = (float*)((char*)d_ws + (512 << 10));
    float* hst = cst + BB * HH;
    float* xwbuf = (float*)((char*)d_ws + (640 << 10));

    // chunk length: multiple of 128 timesteps that fits in remaining workspace
    long long avail = (long long)ws_size - (640 << 10);
    int ctu = 128;
    if (avail > 0) {
        long long mx = avail / ((long long)BB * G4 * 4);  // 256KB per timestep
        int mm = (int)((mx / 128) * 128);
        if (mm >= 128) ctu = mm;
    }
    if (ctu > TT) ctu = TT;

    prep_wh<<<dim3(512), 256, 0, stream>>>(W, whp);
    init_state<<<dim3(64), 256, 0, stream>>>(cst, hst);

    int done = 0;
    while (done < TT) {
        int ct = ctu;
        if (ct > TT - done) ct = TT - done;
        gemm_xw<<<dim3((BB * ct) / BM, G4 / BN), 256, 0, stream>>>(x, W, bias, seqlen, xwbuf, done, ct);
        lstm_chunk<<<dim3(BB), NT, 0, stream>>>(whp, xwbuf, seqlen, y, cst, hst, done, ct);
        done += ct;
    }
}